// Round 3
// 619.656 us; speedup vs baseline: 1.0258x; 1.0258x over previous
//
#include <hip/hip_runtime.h>

// Native 16-byte vector type: clang ext_vector, accepted by the
// __builtin_nontemporal_* builtins (HIP's float4 class type is not).
typedef float v4f __attribute__((ext_vector_type(4)));

// ---------------------------------------------------------------------------
// Kernel A: compute starts[r] and owner[p] using LDS-resident exclusive scans
// instead of per-thread serial O(P) global prefix loops.
//   starts[r] = excl_ps( excl_pp( excl_pf(mod) + field ) + par )
//   owner[p]  = max r with abs_param(r) == p   (last-write-wins scatter)
// Problem sizes: NF=8, NPF=64, P_TOTAL=512 — all fit trivially in LDS.
// ---------------------------------------------------------------------------

#define PF_MAX 256
#define PP_MAX 1024
#define PS_MAX 2048

// Block-wide exclusive scan in LDS (n <= blockDim.x). Hillis-Steele inclusive,
// then subtract own value. All threads must call (syncs are uniform).
__device__ __forceinline__ void excl_scan_lds(int* s, int n, int t) {
    int orig = (t < n) ? s[t] : 0;
    for (int off = 1; off < n; off <<= 1) {
        int v = (t < n && t >= off) ? s[t - off] : 0;
        __syncthreads();
        if (t < n) s[t] += v;
        __syncthreads();
    }
    if (t < n) s[t] -= orig;   // inclusive -> exclusive
    __syncthreads();
}

__global__ void compute_starts_kernel(const int* __restrict__ fields,
                                      const int* __restrict__ ppf,
                                      const int* __restrict__ sp,
                                      const int* __restrict__ coords,
                                      int NF, int NPF, int R, int P_TOTAL,
                                      int* __restrict__ starts,
                                      int* __restrict__ owner) {
    __shared__ int s_pf[PF_MAX];
    __shared__ int s_pp[PP_MAX];
    __shared__ int s_ps[PS_MAX];
    const int t = threadIdx.x;

    if (t < NF && t < PF_MAX)  s_pf[t] = fields[t];
    if (t < NPF && t < PP_MAX) s_pp[t] = ppf[t];
    for (int q = t; q < P_TOTAL && q < PS_MAX; q += blockDim.x) s_ps[q] = sp[q];
    for (int p = t; p < P_TOTAL; p += blockDim.x) owner[p] = -1;
    __syncthreads();

    excl_scan_lds(s_pf, NF, t);
    excl_scan_lds(s_pp, NPF, t);
    excl_scan_lds(s_ps, P_TOTAL, t);

    for (int r = t; r < R; r += blockDim.x) {
        int mod   = coords[3 * r + 0];
        int field = coords[3 * r + 1];
        int par   = coords[3 * r + 2];
        int abs_field = s_pf[mod] + field;
        int abs_param = s_pp[abs_field] + par;
        starts[r] = s_ps[abs_param];
        atomicMax(&owner[abs_param], r);
    }
}

// ---------------------------------------------------------------------------
// Fused kernel: gather (rows [0,R)) and scatter-merge (rows [R, R+P)) in one
// dispatch. The two phases are independent (both depend only on kernel A), so
// fusing removes a launch + inter-kernel drain bubble and lets the scheduler
// interleave them. 4 float4 per thread (16 KB / workgroup).
// Outputs are write-once -> nontemporal stores keep db resident in L2/L3.
// results rows are read at most once (an r maps to exactly one param) ->
// nontemporal loads. db is re-read (gather dups + uncovered merge) -> cached.
// ---------------------------------------------------------------------------
#define VEC 4

__global__ void fused_gather_scatter(const v4f* __restrict__ db,
                                     const v4f* __restrict__ results,
                                     const int* __restrict__ starts,
                                     const int* __restrict__ owner,
                                     v4f* __restrict__ gathered,
                                     v4f* __restrict__ newdb,
                                     int R, int blk4) {
    const int row = blockIdx.y;
    const int j0  = blockIdx.x * (blockDim.x * VEC) + threadIdx.x;

    if (row < R) {
        // gathered[row, :] = db[starts[row] : starts[row]+blk]  (original db)
        const int s4 = starts[row] >> 2;           // starts are multiples of blk
        v4f* dst = gathered + (long long)row * blk4;
#pragma unroll
        for (int k = 0; k < VEC; ++k) {
            int j = j0 + k * (int)blockDim.x;
            if (j < blk4) __builtin_nontemporal_store(db[s4 + j], &dst[j]);
        }
    } else {
        // new_db block p = results[owner[p]] if covered else db block p
        const int p = row - R;
        const int r = owner[p];                    // wave-uniform load
        const long long base = (long long)p * blk4;
        v4f* dst = newdb + base;
        if (r >= 0) {
            const v4f* src = results + (long long)r * blk4;
#pragma unroll
            for (int k = 0; k < VEC; ++k) {
                int j = j0 + k * (int)blockDim.x;
                if (j < blk4)
                    __builtin_nontemporal_store(__builtin_nontemporal_load(&src[j]), &dst[j]);
            }
        } else {
            const v4f* src = db + base;
#pragma unroll
            for (int k = 0; k < VEC; ++k) {
                int j = j0 + k * (int)blockDim.x;
                if (j < blk4) __builtin_nontemporal_store(src[j], &dst[j]);
            }
        }
    }
}

extern "C" void kernel_launch(void* const* d_in, const int* in_sizes, int n_in,
                              void* d_out, int out_size, void* d_ws, size_t ws_size,
                              hipStream_t stream) {
    const float* db      = (const float*)d_in[0];
    const float* results = (const float*)d_in[1];
    const int* fields    = (const int*)d_in[2];
    const int* ppf       = (const int*)d_in[3];
    const int* sp        = (const int*)d_in[4];
    const int* coords    = (const int*)d_in[5];

    const int NF      = in_sizes[2];          // 8
    const int NPF     = in_sizes[3];          // 64
    const int R       = in_sizes[5] / 3;      // 1024
    const int blk     = in_sizes[1] / R;      // 65536
    const int P_TOTAL = in_sizes[4];          // 512

    int* starts = (int*)d_ws;
    int* owner  = starts + R;

    compute_starts_kernel<<<1, 1024, 0, stream>>>(fields, ppf, sp, coords,
                                                  NF, NPF, R, P_TOTAL,
                                                  starts, owner);

    const int blk4 = blk / 4;                           // 16384 float4 per row
    const int per_wg = 256 * VEC;                       // 1024 float4 per wg
    const int gx = (blk4 + per_wg - 1) / per_wg;        // 16

    // Output 0: gathered [R, blk]; Output 1: new_db right after it.
    v4f* gathered = (v4f*)d_out;
    v4f* newdb    = gathered + (long long)R * blk4;

    dim3 grid(gx, R + P_TOTAL);                         // 16 x 1536
    fused_gather_scatter<<<grid, 256, 0, stream>>>((const v4f*)db,
                                                   (const v4f*)results,
                                                   starts, owner,
                                                   gathered, newdb,
                                                   R, blk4);
}